// Round 3
// baseline (402.303 us; speedup 1.0000x reference)
//
#include <hip/hip_runtime.h>
#include <hip/hip_bf16.h>

#define M_DIM 32768   // SEQ*BATCH
#define N_DIM 4096
#define K_DIM 1024

// ---- 256x256 tile, BK=32, 8 waves (2Mx4N), 512 threads, 4-deep LDS ring ----
#define BM 256
#define BN 256
#define BK 32
#define NKT (K_DIM / BK)            // 32
#define TROWS (M_DIM / BM)          // 128
#define TCOLS (N_DIM / BN)          // 16
#define NWG (TROWS * TCOLS)         // 2048
#define BUF_BYTES 32768             // per K-tile: A 16KB + B 16KB

typedef __attribute__((ext_vector_type(4))) float f32x4;
typedef __attribute__((ext_vector_type(8))) short bf16x8;

__device__ __forceinline__ unsigned short f2bf(float f) {
    unsigned int u = __float_as_uint(f);
    u += 0x7FFFu + ((u >> 16) & 1u);   // round-to-nearest-even
    return (unsigned short)(u >> 16);
}

__device__ __forceinline__ void gld_lds16(const void* gsrc, void* ldst) {
    __builtin_amdgcn_global_load_lds(
        (__attribute__((address_space(1))) void*)gsrc,
        (__attribute__((address_space(3))) void*)ldst,
        16, 0, 0);
}

// fp32 -> bf16 pre-cast of X and W into workspace (linear [row][k] layout).
__global__ void cast_kernel(const float* __restrict__ x, const float* __restrict__ w,
                            unsigned short* __restrict__ wsA, unsigned short* __restrict__ wsB) {
    const int nA = M_DIM * (K_DIM / 8);
    const int nB = N_DIM * (K_DIM / 8);
    const int total = nA + nB;
    const int stride = gridDim.x * blockDim.x;
    for (int i = blockIdx.x * blockDim.x + threadIdx.x; i < total; i += stride) {
        const float* src; unsigned short* dst; int g;
        if (i < nA) { src = x; dst = wsA; g = i; }
        else        { src = w; dst = wsB; g = i - nA; }
        const f32x4* s4 = (const f32x4*)(src + (size_t)g * 8);
        f32x4 v0 = s4[0];
        f32x4 v1 = s4[1];
        bf16x8 o;
        o[0] = (short)f2bf(v0[0]); o[1] = (short)f2bf(v0[1]);
        o[2] = (short)f2bf(v0[2]); o[3] = (short)f2bf(v0[3]);
        o[4] = (short)f2bf(v1[0]); o[5] = (short)f2bf(v1[1]);
        o[6] = (short)f2bf(v1[2]); o[7] = (short)f2bf(v1[3]);
        *(bf16x8*)(dst + (size_t)g * 8) = o;
    }
}

// C = A(MxK) * B(NxK)^T + bias.  256x256 tile, BK=32, depth-2 counted-vmcnt
// pipeline over a 4-buffer LDS ring.  Per K-tile:
//   stage(kt+2) -> s_waitcnt vmcnt(8) -> s_barrier -> compute(kt)
// vmcnt(8) = 2 tiles x 4 load-instructions in flight; tile kt's loads were
// issued 2 tiles ago -> no stall, never drains to 0 (T4).  Raw s_barrier
// (NOT __syncthreads -- that emits the vmcnt(0) drain).  Safety: buffer
// (kt+2)&3 was last read at compute(kt-2), complete before barrier@kt-1,
// which precedes this stage in every wave's program order.
// LDS layout per buffer: A[256 rows][4 slots of 16B], slot ^= (row>>1)&3
// (each 16-lane quarter-wave covers all 32 banks 2-way = free).  Swizzle is
// applied on the global SOURCE (global_load_lds writes linearly) and again
// on ds_read (both-sides rule).
__global__ __launch_bounds__(512, 2)
void gemm_kernel(const unsigned short* __restrict__ Abf,
                 const unsigned short* __restrict__ Bbf,
                 const float* __restrict__ bias, float* __restrict__ C) {
    __shared__ unsigned char smem[4 * BUF_BYTES];   // 128 KiB

    const int t    = threadIdx.x;                   // 0..511
    const int lane = t & 63;
    const int wave = t >> 6;                        // 0..7
    const int wr   = wave >> 2;                     // 0..1  (M)
    const int wc   = wave & 3;                      // 0..3  (N)

    // XCD-aware block mapping: per-XCD row-major over its 16x16 tile chunk.
    // A-panel (512 KB) is reused by 16 consecutive tiles within the XCD's L2.
    const int bid  = blockIdx.x;
    const int xcd  = bid & 7;
    const int j    = bid >> 3;                      // 0..255
    const int trow = xcd * (TROWS / 8) + (j >> 4);  // 16 rows per XCD
    const int tcol = j & 15;
    const int row0 = trow * BM;
    const int col0 = tcol * BN;

    // ---- staging source offsets (pre-swizzled global source) ----
    // LDS slot index lam (16B units): row = lam>>2, s = lam&3,
    // sourced from global k8-group jsrc = s ^ ((row>>1)&3).
    const int rA0 = t >> 2;                         // 0..127
    const int rA1 = rA0 + 128;
    const int s0  = t & 3;
    const int j0  = s0 ^ ((rA0 >> 1) & 3);          // == for rA1 (128 = 0 mod 4*2)
    const size_t sA0 = (size_t)(row0 + rA0) * K_DIM + j0 * 8;
    const size_t sA1 = (size_t)(row0 + rA1) * K_DIM + j0 * 8;
    const size_t sB0 = (size_t)(col0 + rA0) * K_DIM + j0 * 8;
    const size_t sB1 = (size_t)(col0 + rA1) * K_DIM + j0 * 8;

    auto stage = [&](int kt) {
        unsigned char* buf = smem + (size_t)(kt & 3) * BUF_BYTES;
        const int kofs = kt * BK;
        gld_lds16(Abf + sA0 + kofs, buf + (size_t)t * 16);
        gld_lds16(Abf + sA1 + kofs, buf + (size_t)(t + 512) * 16);
        gld_lds16(Bbf + sB0 + kofs, buf + 16384 + (size_t)t * 16);
        gld_lds16(Bbf + sB1 + kofs, buf + 16384 + (size_t)(t + 512) * 16);
    };

    // ---- ds_read offsets (swizzled on read) ----
    const int laneR = lane & 15;
    const int jb    = lane >> 4;                    // k8-group 0..3
    int offA[8], offB[4];
    #pragma unroll
    for (int m = 0; m < 8; ++m) {
        const int r = wr * 128 + m * 16 + laneR;
        offA[m] = r * 64 + ((jb ^ ((r >> 1) & 3)) * 16);
    }
    #pragma unroll
    for (int n = 0; n < 4; ++n) {
        const int r = wc * 64 + n * 16 + laneR;
        offB[n] = 16384 + r * 64 + ((jb ^ ((r >> 1) & 3)) * 16);
    }

    f32x4 acc[8][4] = {};

    auto compute = [&](int kt) {
        const unsigned char* buf = smem + (size_t)(kt & 3) * BUF_BYTES;
        bf16x8 a[8], b[4];
        #pragma unroll
        for (int m = 0; m < 8; ++m) a[m] = *(const bf16x8*)(buf + offA[m]);
        #pragma unroll
        for (int n = 0; n < 4; ++n) b[n] = *(const bf16x8*)(buf + offB[n]);
        __builtin_amdgcn_s_setprio(1);
        #pragma unroll
        for (int m = 0; m < 8; ++m)
            #pragma unroll
            for (int n = 0; n < 4; ++n)
                acc[m][n] = __builtin_amdgcn_mfma_f32_16x16x32_bf16(
                    a[m], b[n], acc[m][n], 0, 0, 0);
        __builtin_amdgcn_s_setprio(0);
    };

    // ---- prologue: 2 tiles in flight ----
    stage(0);
    stage(1);

    // ---- main loop ----
    #pragma unroll
    for (int kt = 0; kt < NKT - 2; ++kt) {
        stage(kt + 2);
        asm volatile("s_waitcnt vmcnt(8)" ::: "memory");
        __builtin_amdgcn_s_barrier();
        asm volatile("" ::: "memory");   // keep ds_reads below the barrier
        compute(kt);
    }
    // ---- epilogue: drain 4 -> 0 ----
    asm volatile("s_waitcnt vmcnt(4)" ::: "memory");
    __builtin_amdgcn_s_barrier();
    asm volatile("" ::: "memory");
    compute(NKT - 2);
    asm volatile("s_waitcnt vmcnt(0)" ::: "memory");
    __builtin_amdgcn_s_barrier();
    asm volatile("" ::: "memory");
    compute(NKT - 1);

    // ---- C write: frag layout col = lane&15, row = (lane>>4)*4 + reg ----
    const int cr = (lane >> 4) * 4;
    const int cc = lane & 15;
    float bv[4];
    #pragma unroll
    for (int n = 0; n < 4; ++n)
        bv[n] = bias[col0 + wc * 64 + n * 16 + cc];
    #pragma unroll
    for (int m = 0; m < 8; ++m) {
        const int gr = row0 + wr * 128 + m * 16 + cr;
        #pragma unroll
        for (int n = 0; n < 4; ++n) {
            const int gc = col0 + wc * 64 + n * 16 + cc;
            float* p = C + (size_t)gr * N_DIM + gc;
            p[0]                 = acc[m][n][0] + bv[n];
            p[(size_t)N_DIM]     = acc[m][n][1] + bv[n];
            p[(size_t)2 * N_DIM] = acc[m][n][2] + bv[n];
            p[(size_t)3 * N_DIM] = acc[m][n][3] + bv[n];
        }
    }
}

// Fallback (no workspace): round-2 verified 128x128 fused-cast kernel.
__global__ __launch_bounds__(256, 4)
void gemm_fallback(const float* __restrict__ Af, const float* __restrict__ Bf,
                   const float* __restrict__ bias, float* __restrict__ C) {
    __shared__ unsigned char smem[32768];
    const int t = threadIdx.x, lane = t & 63, wave = t >> 6;
    const int wr = wave >> 1, wc = wave & 1;
    const int bid = blockIdx.x;
    const int swz = (bid & 7) * ((M_DIM / 128) * (N_DIM / 128) / 8) + (bid >> 3);
    const int row0 = (swz / (N_DIM / 128)) * 128;
    const int col0 = (swz % (N_DIM / 128)) * 128;
    const int srow = t >> 3;
    const int sj   = (t & 7) ^ (srow & 7);
    const int aoff0 = (row0 + srow) * K_DIM + sj * 8;
    const int boff0 = (col0 + srow) * K_DIM + sj * 8;
    f32x4 acc[4][4] = {};
    const int laneR = lane & 15, jb = lane >> 4, lx = lane & 7;
    f32x4 ra[4][2], rb[4][2];
    for (int kt = 0; kt < K_DIM / 64; ++kt) {
        const int kofs = kt * 64;
        #pragma unroll
        for (int i = 0; i < 4; ++i) {
            const float* pa = Af + aoff0 + i * (32 * K_DIM) + kofs;
            ra[i][0] = *(const f32x4*)pa; ra[i][1] = *(const f32x4*)(pa + 4);
            const float* pb = Bf + boff0 + i * (32 * K_DIM) + kofs;
            rb[i][0] = *(const f32x4*)pb; rb[i][1] = *(const f32x4*)(pb + 4);
        }
        #pragma unroll
        for (int i = 0; i < 4; ++i) {
            bf16x8 oa, ob;
            #pragma unroll
            for (int q = 0; q < 4; ++q) {
                oa[q] = (short)f2bf(ra[i][0][q]); oa[q + 4] = (short)f2bf(ra[i][1][q]);
                ob[q] = (short)f2bf(rb[i][0][q]); ob[q + 4] = (short)f2bf(rb[i][1][q]);
            }
            *(bf16x8*)(smem + i * 4096 + t * 16) = oa;
            *(bf16x8*)(smem + 16384 + i * 4096 + t * 16) = ob;
        }
        __syncthreads();
        #pragma unroll
        for (int kk = 0; kk < 2; ++kk) {
            bf16x8 af[4], bfr[4];
            #pragma unroll
            for (int m = 0; m < 4; ++m) {
                const int r = wr * 64 + m * 16 + laneR;
                af[m] = *(const bf16x8*)(smem + r * 128 + (((kk * 4 + jb) ^ lx) * 16));
            }
            #pragma unroll
            for (int n = 0; n < 4; ++n) {
                const int r = wc * 64 + n * 16 + laneR;
                bfr[n] = *(const bf16x8*)(smem + 16384 + r * 128 + (((kk * 4 + jb) ^ lx) * 16));
            }
            #pragma unroll
            for (int m = 0; m < 4; ++m)
                #pragma unroll
                for (int n = 0; n < 4; ++n)
                    acc[m][n] = __builtin_amdgcn_mfma_f32_16x16x32_bf16(
                        af[m], bfr[n], acc[m][n], 0, 0, 0);
        }
        __syncthreads();
    }
    const int cr = (lane >> 4) * 4, cc = lane & 15;
    float bv[4];
    #pragma unroll
    for (int n = 0; n < 4; ++n) bv[n] = bias[col0 + wc * 64 + n * 16 + cc];
    #pragma unroll
    for (int m = 0; m < 4; ++m) {
        const int gr = row0 + wr * 64 + m * 16 + cr;
        #pragma unroll
        for (int n = 0; n < 4; ++n) {
            const int gc = col0 + wc * 64 + n * 16 + cc;
            float* p = C + (size_t)gr * N_DIM + gc;
            p[0]                 = acc[m][n][0] + bv[n];
            p[(size_t)N_DIM]     = acc[m][n][1] + bv[n];
            p[(size_t)2 * N_DIM] = acc[m][n][2] + bv[n];
            p[(size_t)3 * N_DIM] = acc[m][n][3] + bv[n];
        }
    }
}

extern "C" void kernel_launch(void* const* d_in, const int* in_sizes, int n_in,
                              void* d_out, int out_size, void* d_ws, size_t ws_size,
                              hipStream_t stream) {
    const float* x    = (const float*)d_in[0];
    const float* w    = (const float*)d_in[1];
    const float* bias = (const float*)d_in[2];
    float* out        = (float*)d_out;

    const size_t needA = (size_t)M_DIM * K_DIM * sizeof(unsigned short);
    const size_t needB = (size_t)N_DIM * K_DIM * sizeof(unsigned short);

    if (ws_size >= needA + needB) {
        unsigned short* wsA = (unsigned short*)d_ws;
        unsigned short* wsB = wsA + (size_t)M_DIM * K_DIM;
        cast_kernel<<<4096, 256, 0, stream>>>(x, w, wsA, wsB);
        gemm_kernel<<<NWG, 512, 0, stream>>>(wsA, wsB, bias, out);
    } else {
        gemm_fallback<<<(M_DIM / 128) * (N_DIM / 128), 256, 0, stream>>>(x, w, bias, out);
    }
}